// Round 3
// baseline (5802.062 us; speedup 1.0000x reference)
//
// R3: = R2 with the output dtype corrected to FLOAT32.
// Evidence: out_npz_mb=64.9 => 17.5M fp32 elements (~70MB raw); bit-identical error
// across R1/R2 (2.851562 = max|ref| + small) matches fp32-reading of a half-filled
// ushort buffer. Comparison happens in bf16 space (threshold 8*2^-8*max|ref|), so the
// bf16 MFMA chain accuracy is sufficient -- only the store dtype was wrong.
#include <hip/hip_runtime.h>

typedef __bf16 bf16x8 __attribute__((ext_vector_type(8)));
typedef unsigned short u16x8 __attribute__((ext_vector_type(8)));
typedef float f32x4 __attribute__((ext_vector_type(4)));
typedef unsigned short u16a __attribute__((may_alias));
typedef u16x8 u16x8a __attribute__((may_alias));
typedef bf16x8 bf16x8a __attribute__((may_alias));

#define MFMA16(a,b,c) __builtin_amdgcn_mfma_f32_16x16x32_bf16(a,b,c,0,0,0)

// ---------------- ws layout ----------------
// doubles @ byte 0
#define WD_SX   0
#define WD_SXX  1
#define WD_SP2  2
#define WD_SQ2  130
#define WD_SP3  258
#define WD_SQ3  386   // end 514 doubles
// f32 atomics/bins @ byte 8192
#define WB_B1X  0       // 32
#define WB_B1C  32      // 32
#define WB_B2   64      // 27*128
#define WB_B3   (64+27*128)
#define ZERO_BYTES (8192 + (64 + 2*27*128)*4)
// f32 params @ byte 49152
#define WP_A    0
#define WP_B    128
#define WP_C2   256
#define WP_D2F  384
#define WP_C3   512
#define WP_D3F  640
#define WP_H1S  1024
#define WP_H2S  (1024+3456)
// bf16 (ushort) weights @ byte 81920
#define WU_W2RT 0
#define WU_W3RT 16384
#define WU_HW1T 32768
#define WU_EW1T 65536
#define WU_RW1T 98304
#define WU_HW2T 131072   // 16x256 (padded from 8)
#define WU_EW2T 135168   // 32x256 (padded from 18)
#define WU_RW2T 143360   // 16x256 (padded from 9)
#define WU_TOTAL 147456
#define WS_NEED (81920 + WU_TOTAL*2)

__device__ inline unsigned short f2bf(float f){
  union { float f; unsigned u; } v; v.f = f;
  return (unsigned short)((v.u + 0x7FFFu + ((v.u >> 16) & 1u)) >> 16);
}
__device__ inline float bf2f(unsigned short h){
  union { unsigned u; float f; } v; v.u = ((unsigned)h) << 16;
  return v.f;
}
__device__ inline bf16x8 u2b(u16x8 u){ union { u16x8 u; bf16x8 b; } c; c.u = u; return c.b; }

// build the layer-1 A-fragment: row = lane&15 -> node, k = coeff index
__device__ inline bf16x8 h1frag(const float* __restrict__ Ac, const float* __restrict__ Bc,
                                float xv, int kb){
  u16x8 a;
#pragma unroll
  for (int j = 0; j < 8; j++)
    a[j] = f2bf(fmaxf(fmaf(Ac[kb + j], xv, Bc[kb + j]), 0.f));
  return u2b(a);
}
__device__ inline bf16x8 ldg8(const unsigned short* __restrict__ p){
  return *(const bf16x8a*)p;
}
// LDS bf16 tile helpers, XOR row swizzle; may_alias keeps store->load ordered
__device__ inline bf16x8 lda8(const unsigned short* base, int r, int k, int rb){
  int byte = (r * rb + k * 2) ^ ((r & 7) << 4);
  u16x8 u = *(const u16x8a*)((const char*)base + byte);
  return u2b(u);
}
__device__ inline void sth(unsigned short* base, int r, int c, int rb, float v){
  int byte = (r * rb + c * 2) ^ ((r & 7) << 4);
  *(u16a*)((char*)base + byte) = f2bf(v);
}

// ---------------- small kernels ----------------
__global__ void k_prep(const float* __restrict__ w2r, const float* __restrict__ w3r,
                       const float* __restrict__ hw1, const float* __restrict__ ew1,
                       const float* __restrict__ rw1, const float* __restrict__ hw2,
                       const float* __restrict__ ew2, const float* __restrict__ rw2,
                       unsigned short* __restrict__ wsU){
  int i = blockIdx.x * blockDim.x + threadIdx.x;
  if (i < 16384){ int c=i>>7,k=i&127; wsU[WU_W2RT+i]=f2bf(w2r[k*128+c]); return; } i -= 16384;
  if (i < 16384){ int c=i>>7,k=i&127; wsU[WU_W3RT+i]=f2bf(w3r[k*128+c]); return; } i -= 16384;
  if (i < 32768){ int c=i>>7,k=i&127; wsU[WU_HW1T+i]=f2bf(hw1[k*256+c]); return; } i -= 32768;
  if (i < 32768){ int c=i>>7,k=i&127; wsU[WU_EW1T+i]=f2bf(ew1[k*256+c]); return; } i -= 32768;
  if (i < 32768){ int c=i>>7,k=i&127; wsU[WU_RW1T+i]=f2bf(rw1[k*256+c]); return; } i -= 32768;
  if (i < 4096) { int c=i>>8,k=i&255; wsU[WU_HW2T+i]=f2bf(c<8 ? hw2[k*8+c] :0.f); return; } i -= 4096;
  if (i < 8192) { int c=i>>8,k=i&255; wsU[WU_EW2T+i]=f2bf(c<18? ew2[k*18+c]:0.f); return; } i -= 8192;
  if (i < 4096) { int c=i>>8,k=i&255; wsU[WU_RW2T+i]=f2bf(c<9 ? rw2[k*9+c] :0.f); return; }
}

__global__ void k_bins1(const float* __restrict__ x, const int* __restrict__ dst,
                        float* __restrict__ wsB, int nh){
  __shared__ float lb[64];
  if (threadIdx.x < 64) lb[threadIdx.x] = 0.f;
  __syncthreads();
  for (int i = blockIdx.x * blockDim.x + threadIdx.x; i < nh; i += gridDim.x * blockDim.x){
    float xv = x[i];
    int d1 = dst[i] - nh, d2 = dst[i + nh] - nh;
    atomicAdd(&lb[d1], xv);      atomicAdd(&lb[32 + d1], 1.f);
    atomicAdd(&lb[d2], xv);      atomicAdd(&lb[32 + d2], 1.f);
  }
  __syncthreads();
  if (threadIdx.x < 64) atomicAdd(wsB + threadIdx.x, lb[threadIdx.x]); // [0,32)=sum x, [32,64)=cnt
}

__global__ void k_xmom(const float* __restrict__ x, double* __restrict__ wsD, int N){
  double s = 0, q = 0;
  for (int i = blockIdx.x * blockDim.x + threadIdx.x; i < N; i += gridDim.x * blockDim.x){
    double v = x[i]; s += v; q += v * v;
  }
#pragma unroll
  for (int o = 32; o; o >>= 1){ s += __shfl_down(s, o); q += __shfl_down(q, o); }
  if ((threadIdx.x & 63) == 0){ atomicAdd(wsD + WD_SX, s); atomicAdd(wsD + WD_SXX, q); }
}

__global__ void k_S1(const float* __restrict__ x, const float* __restrict__ w1l,
                     const float* __restrict__ w1r, const float* __restrict__ b1,
                     const float* __restrict__ g1w, const float* __restrict__ g1b,
                     const float* __restrict__ g1m, const float* __restrict__ wsB,
                     const double* __restrict__ wsD, float* __restrict__ wsP, int nh, int N){
  __shared__ float pres[27 * 128];
  int c = threadIdx.x;                     // 128 threads
  double Sx = wsD[WD_SX], Sxx = wsD[WD_SXX];
  const float* bx = wsB + WB_B1X; const float* bc = wsB + WB_B1C;
  double sumQ = 0, xs = 0, xs2 = 0, Sm = 0;
  double wl = w1l[c], wr = w1r[c], bb = b1[c];
  for (int j = 0; j < 27; j++){
    double xj = (double)x[nh + j];
    xs += xj; xs2 += xj * xj;
    double mj = (double)bx[j] / fmax((double)bc[j], 1.0);
    Sm += mj;
    double pre = mj * wl + xj * wr + bb;
    pres[j * 128 + c] = (float)pre;
    sumQ += pre * pre;
  }
  double S1 = wr * Sx + (double)N * bb + wl * Sm;
  double mu = S1 / N;
  double Sxh = Sx - xs, Sxxh = Sxx - xs2;
  double Q = wr * wr * Sxxh + 2.0 * wr * bb * Sxh + (double)nh * bb * bb + sumQ;
  double ms = g1m[c];
  double var = Q / N - 2.0 * ms * mu * mu + ms * ms * mu * mu;
  double inv = 1.0 / sqrt(var + 1e-5);
  float C1 = (float)((double)g1w[c] * inv);
  float D1 = (float)((double)g1b[c] - (double)g1w[c] * inv * ms * mu);
  wsP[WP_A + c] = C1 * (float)wr;
  wsP[WP_B + c] = fmaf(C1, (float)bb, D1);
  for (int j = 0; j < 27; j++)
    wsP[WP_H1S + j * 128 + c] = fmaxf(fmaf(C1, pres[j * 128 + c], D1), 0.f);
}

// super-node layer + stats finalize for layers 2/3
__global__ void k_S23(const float* __restrict__ binsNg, const float* __restrict__ cnt,
                      const float* __restrict__ hsup_in, const float* __restrict__ wl,
                      const float* __restrict__ wr, const float* __restrict__ bb,
                      const float* __restrict__ gw, const float* __restrict__ gb,
                      const float* __restrict__ gm, const double* __restrict__ spD,
                      const double* __restrict__ sqD, float* __restrict__ Cout,
                      float* __restrict__ Dfout, float* __restrict__ hsup_out, int nh, int N){
  __shared__ float mloc[27 * 128], hloc[27 * 128], pres[27 * 128];
  __shared__ float sC[128], sD[128];
  int tid = threadIdx.x;                   // 256 threads
  for (int i = tid; i < 27 * 128; i += 256){
    int j = i >> 7;
    mloc[i] = binsNg[i] / fmaxf(cnt[j], 1.f);
    hloc[i] = hsup_in[i];
  }
  __syncthreads();
  int c = tid & 127, g = tid >> 7;
  for (int j = g; j < 27; j += 2){
    float acc = bb[c];
#pragma unroll 4
    for (int k = 0; k < 128; k++)
      acc += mloc[j * 128 + k] * wl[k * 128 + c] + hloc[j * 128 + k] * wr[k * 128 + c];
    pres[j * 128 + c] = acc;
  }
  __syncthreads();
  if (tid < 128){
    double sumP = 0, sumQ = 0;
    for (int j = 0; j < 27; j++){ double p = pres[j * 128 + c]; sumP += p; sumQ += p * p; }
    double mu = (spD[c] + sumP) / N;
    double E2 = (sqD[c] + sumQ) / N;
    double ms = gm[c];
    double var = E2 - 2.0 * ms * mu * mu + ms * ms * mu * mu;
    double inv = 1.0 / sqrt(var + 1e-5);
    float C = (float)((double)gw[c] * inv);
    float D = (float)((double)gb[c] - (double)gw[c] * inv * ms * mu);
    Cout[c] = C;
    Dfout[c] = fmaf(C, bb[c], D);   // folded: h = relu(C*acc + Df), acc excludes bias
    sC[c] = C; sD[c] = D;
  }
  __syncthreads();
  if (hsup_out){
    for (int i = tid; i < 27 * 128; i += 256){
      int cc = i & 127;
      hsup_out[i] = fmaxf(fmaf(sC[cc], pres[i], sD[cc]), 0.f);
    }
  }
}

// bins of h1 by dst (layer-2 super inputs)
__global__ __launch_bounds__(256) void k_binh1(const float* __restrict__ x,
                                               const int* __restrict__ dst,
                                               const float* __restrict__ wsP,
                                               float* __restrict__ bins2g, int nh){
  __shared__ float lb[2][27 * 128];
  int tid = threadIdx.x;
  for (int i = tid; i < 2 * 27 * 128; i += 256) ((float*)lb)[i] = 0.f;
  __syncthreads();
  int c = tid & 127, g = tid >> 7;
  float Ac = wsP[WP_A + c], Bc = wsP[WP_B + c];
  float* mb = lb[g];
  for (int n0 = blockIdx.x * 8 + g * 4; n0 < nh; n0 += gridDim.x * 8){
    float xv[4]; int dd1[4], dd2[4];
#pragma unroll
    for (int u = 0; u < 4; u++){
      int n = n0 + u; bool v = n < nh;
      xv[u] = v ? x[n] : 0.f;
      dd1[u] = v ? dst[n] - nh : 0;
      dd2[u] = v ? dst[n + nh] - nh : 0;
    }
#pragma unroll
    for (int u = 0; u < 4; u++){
      if (n0 + u < nh){
        float h = fmaxf(fmaf(Ac, xv[u], Bc), 0.f);
        mb[dd1[u] * 128 + c] += h;
        mb[dd2[u] * 128 + c] += h;
      }
    }
  }
  __syncthreads();
  for (int i = tid; i < 27 * 128; i += 256) atomicAdd(bins2g + i, lb[0][i] + lb[1][i]);
}

// ---------------- MFMA passes ----------------
__global__ __launch_bounds__(256) void k_passA(const float* __restrict__ x,
    const float* __restrict__ wsP, const unsigned short* __restrict__ wsU,
    const float* __restrict__ b2, double* __restrict__ wsD, int nh, int tiles){
  const float* Ac = wsP + WP_A; const float* Bc = wsP + WP_B;
  const unsigned short* w2rT = wsU + WU_W2RT;
  int l = threadIdx.x & 63, w = threadIdx.x >> 6;
  int l15 = l & 15, lg = l >> 4;
  float s[8], q[8];
#pragma unroll
  for (int i = 0; i < 8; i++){ s[i] = 0; q[i] = 0; }
  for (int t = blockIdx.x; t < tiles; t += gridDim.x){
    int r0 = t * 64 + w * 16;
    int ra = r0 + l15;
    float xv = (ra < nh) ? x[ra] : 0.f;
    bf16x8 af[4];
#pragma unroll
    for (int ks = 0; ks < 4; ks++) af[ks] = h1frag(Ac, Bc, xv, ks * 32 + lg * 8);
#pragma unroll
    for (int ct = 0; ct < 8; ct++){
      f32x4 acc = {0, 0, 0, 0};
#pragma unroll
      for (int ks = 0; ks < 4; ks++)
        acc = MFMA16(af[ks], ldg8(w2rT + (ct * 16 + l15) * 128 + ks * 32 + lg * 8), acc);
      float bb = b2[ct * 16 + l15];
#pragma unroll
      for (int i = 0; i < 4; i++){
        if (r0 + lg * 4 + i < nh){ float p = acc[i] + bb; s[ct] += p; q[ct] += p * p; }
      }
    }
  }
#pragma unroll
  for (int i = 0; i < 8; i++){
    s[i] += __shfl_xor(s[i], 16); s[i] += __shfl_xor(s[i], 32);
    q[i] += __shfl_xor(q[i], 16); q[i] += __shfl_xor(q[i], 32);
  }
  __shared__ float red[2][4][128];
  if (lg == 0){
#pragma unroll
    for (int ct = 0; ct < 8; ct++){ red[0][w][ct * 16 + l15] = s[ct]; red[1][w][ct * 16 + l15] = q[ct]; }
  }
  __syncthreads();
  if (threadIdx.x < 128){
    int c = threadIdx.x;
    atomicAdd(wsD + WD_SP2 + c, (double)(red[0][0][c] + red[0][1][c] + red[0][2][c] + red[0][3][c]));
    atomicAdd(wsD + WD_SQ2 + c, (double)(red[1][0][c] + red[1][1][c] + red[1][2][c] + red[1][3][c]));
  }
}

__global__ __launch_bounds__(256) void k_passB(const float* __restrict__ x,
    const int* __restrict__ dst, const float* __restrict__ wsP,
    const unsigned short* __restrict__ wsU, const float* __restrict__ b3,
    double* __restrict__ wsD, float* __restrict__ bins3g, int nh, int tiles){
  __shared__ float binsW[4][27 * 128];
  __shared__ unsigned short h2all[4][2048];
  __shared__ float red[2][4][128];
  int tid = threadIdx.x;
  for (int i = tid; i < 4 * 27 * 128; i += 256) ((float*)binsW)[i] = 0.f;
  __syncthreads();
  int l = tid & 63, w = tid >> 6, l15 = l & 15, lg = l >> 4;
  unsigned short* h2l = h2all[w];
  const float* Ac = wsP + WP_A; const float* Bc = wsP + WP_B;
  const float* C2 = wsP + WP_C2; const float* D2 = wsP + WP_D2F;
  const unsigned short* w2rT = wsU + WU_W2RT; const unsigned short* w3rT = wsU + WU_W3RT;
  float s[8], q[8];
#pragma unroll
  for (int i = 0; i < 8; i++){ s[i] = 0; q[i] = 0; }
  for (int t = blockIdx.x; t < tiles; t += gridDim.x){
    __syncthreads();   // WAR: protect previous iteration's h2l reads before overwrite
    int r0 = t * 64 + w * 16;
    float xv = (r0 + l15 < nh) ? x[r0 + l15] : 0.f;
    bf16x8 af[4];
#pragma unroll
    for (int ks = 0; ks < 4; ks++) af[ks] = h1frag(Ac, Bc, xv, ks * 32 + lg * 8);
#pragma unroll
    for (int ct = 0; ct < 8; ct++){
      f32x4 acc = {0, 0, 0, 0};
#pragma unroll
      for (int ks = 0; ks < 4; ks++)
        acc = MFMA16(af[ks], ldg8(w2rT + (ct * 16 + l15) * 128 + ks * 32 + lg * 8), acc);
      int c = ct * 16 + l15; float c2 = C2[c], d2 = D2[c];
#pragma unroll
      for (int i = 0; i < 4; i++)
        sth(h2l, lg * 4 + i, c, 256, fmaxf(fmaf(c2, acc[i], d2), 0.f));
    }
    __syncthreads();   // RAW: h2l stores -> a2 loads
    bf16x8 a2[4];
#pragma unroll
    for (int ks = 0; ks < 4; ks++) a2[ks] = lda8(h2l, l15, ks * 32 + lg * 8, 256);
#pragma unroll
    for (int ct = 0; ct < 8; ct++){
      f32x4 acc = {0, 0, 0, 0};
#pragma unroll
      for (int ks = 0; ks < 4; ks++)
        acc = MFMA16(a2[ks], ldg8(w3rT + (ct * 16 + l15) * 128 + ks * 32 + lg * 8), acc);
      float bb = b3[ct * 16 + l15];
#pragma unroll
      for (int i = 0; i < 4; i++){
        if (r0 + lg * 4 + i < nh){ float p = acc[i] + bb; s[ct] += p; q[ct] += p * p; }
      }
    }
    // segment bins of h2 (layer-3 super inputs); wave-private, no race
    for (int rr = 0; rr < 16; rr++){
      int node = r0 + rr;
      if (node < nh){
        int d1 = dst[node] - nh, d2i = dst[node + nh] - nh;
#pragma unroll
        for (int half = 0; half < 2; half++){
          int c = l + half * 64;
          int byte = (rr * 256 + c * 2) ^ ((rr & 7) << 4);
          float hv = bf2f(*(const u16a*)((const char*)h2l + byte));
          binsW[w][d1 * 128 + c] += hv;
          binsW[w][d2i * 128 + c] += hv;
        }
      }
    }
  }
#pragma unroll
  for (int i = 0; i < 8; i++){
    s[i] += __shfl_xor(s[i], 16); s[i] += __shfl_xor(s[i], 32);
    q[i] += __shfl_xor(q[i], 16); q[i] += __shfl_xor(q[i], 32);
  }
  if (lg == 0){
#pragma unroll
    for (int ct = 0; ct < 8; ct++){ red[0][w][ct * 16 + l15] = s[ct]; red[1][w][ct * 16 + l15] = q[ct]; }
  }
  __syncthreads();
  if (tid < 128){
    atomicAdd(wsD + WD_SP3 + tid, (double)(red[0][0][tid] + red[0][1][tid] + red[0][2][tid] + red[0][3][tid]));
    atomicAdd(wsD + WD_SQ3 + tid, (double)(red[1][0][tid] + red[1][1][tid] + red[1][2][tid] + red[1][3][tid]));
  }
  for (int i = tid; i < 27 * 128; i += 256)
    atomicAdd(bins3g + i, binsW[0][i] + binsW[1][i] + binsW[2][i] + binsW[3][i]);
}

__global__ __launch_bounds__(256) void k_passC(const float* __restrict__ x,
    const float* __restrict__ wsP, const unsigned short* __restrict__ wsU,
    const float* __restrict__ hb1, const float* __restrict__ hb2,
    const float* __restrict__ eb1, const float* __restrict__ eb2,
    const float* __restrict__ rb1, const float* __restrict__ rb2,
    float* __restrict__ out, int nh, int tiles){
  __shared__ char lds[65536];
  int tid = threadIdx.x;
  int l = tid & 63, w = tid >> 6, l15 = l & 15, lg = l >> 4;
  char* myl = lds + w * 16384;                       // wave-private tiles
  unsigned short* h2l = (unsigned short*)myl;        // 16x128 bf16, row 256 B
  unsigned short* h3l = (unsigned short*)(myl + 4096);
  unsigned short* tl  = (unsigned short*)(myl + 8192); // 16x256 bf16, row 512 B
  const float* Ac = wsP + WP_A;  const float* Bc = wsP + WP_B;
  const float* C2 = wsP + WP_C2; const float* D2 = wsP + WP_D2F;
  const float* C3 = wsP + WP_C3; const float* D3 = wsP + WP_D3F;
  const unsigned short* w2rT = wsU + WU_W2RT; const unsigned short* w3rT = wsU + WU_W3RT;
  const unsigned short* W1Ts[3] = {wsU + WU_HW1T, wsU + WU_EW1T, wsU + WU_RW1T};
  const unsigned short* W2Ts[3] = {wsU + WU_HW2T, wsU + WU_EW2T, wsU + WU_RW2T};
  const float* B1s[3] = {hb1, eb1, rb1};
  const float* B2s[3] = {hb2, eb2, rb2};
  const int ncolss[3] = {8, 18, 9};
  const int ncts[3]   = {1, 2, 1};
  float* outs[3] = {out, out + (size_t)nh * 8, out + (size_t)nh * 26};

  for (int t = blockIdx.x; t < tiles; t += gridDim.x){
    int r0 = t * 64 + w * 16;
    int ra = r0 + l15;
    float xv = (ra < nh) ? x[ra] : 0.f;
    bf16x8 af[4];
#pragma unroll
    for (int ks = 0; ks < 4; ks++) af[ks] = h1frag(Ac, Bc, xv, ks * 32 + lg * 8);
    // GEMM1 -> h2
#pragma unroll
    for (int ct = 0; ct < 8; ct++){
      f32x4 acc = {0, 0, 0, 0};
#pragma unroll
      for (int ks = 0; ks < 4; ks++)
        acc = MFMA16(af[ks], ldg8(w2rT + (ct * 16 + l15) * 128 + ks * 32 + lg * 8), acc);
      int c = ct * 16 + l15; float c2 = C2[c], d2 = D2[c];
#pragma unroll
      for (int i = 0; i < 4; i++)
        sth(h2l, lg * 4 + i, c, 256, fmaxf(fmaf(c2, acc[i], d2), 0.f));
    }
    __syncthreads();   // h2l stores -> a2 loads
    // GEMM2 -> h3
    bf16x8 a2[4];
#pragma unroll
    for (int ks = 0; ks < 4; ks++) a2[ks] = lda8(h2l, l15, ks * 32 + lg * 8, 256);
#pragma unroll
    for (int ct = 0; ct < 8; ct++){
      f32x4 acc = {0, 0, 0, 0};
#pragma unroll
      for (int ks = 0; ks < 4; ks++)
        acc = MFMA16(a2[ks], ldg8(w3rT + (ct * 16 + l15) * 128 + ks * 32 + lg * 8), acc);
      int c = ct * 16 + l15; float c3 = C3[c], d3 = D3[c];
#pragma unroll
      for (int i = 0; i < 4; i++)
        sth(h3l, lg * 4 + i, c, 256, fmaxf(fmaf(c3, acc[i], d3), 0.f));
    }
    __syncthreads();   // h3l stores -> a3 loads
    bf16x8 a3[4];
#pragma unroll
    for (int ks = 0; ks < 4; ks++) a3[ks] = lda8(h3l, l15, ks * 32 + lg * 8, 256);
    // three heads
#pragma unroll
    for (int hd = 0; hd < 3; hd++){
      __syncthreads(); // WAR: previous head's tl reads before overwrite
      const unsigned short* W1T = W1Ts[hd]; const float* B1 = B1s[hd];
#pragma unroll
      for (int ct = 0; ct < 16; ct++){
        f32x4 acc = {0, 0, 0, 0};
#pragma unroll
        for (int ks = 0; ks < 4; ks++)
          acc = MFMA16(a3[ks], ldg8(W1T + (ct * 16 + l15) * 128 + ks * 32 + lg * 8), acc);
        int c = ct * 16 + l15; float b1v = B1[c];
#pragma unroll
        for (int i = 0; i < 4; i++)
          sth(tl, lg * 4 + i, c, 512, fmaxf(acc[i] + b1v, 0.f));
      }
      __syncthreads(); // tl stores -> a4 loads
      const unsigned short* W2T = W2Ts[hd];
      int nct = ncts[hd];
      f32x4 acc4[2];
      acc4[0] = (f32x4){0, 0, 0, 0}; acc4[1] = (f32x4){0, 0, 0, 0};
#pragma unroll
      for (int ks = 0; ks < 8; ks++){
        bf16x8 a4 = lda8(tl, l15, ks * 32 + lg * 8, 512);
        acc4[0] = MFMA16(a4, ldg8(W2T + l15 * 256 + ks * 32 + lg * 8), acc4[0]);
        if (nct > 1)
          acc4[1] = MFMA16(a4, ldg8(W2T + (16 + l15) * 256 + ks * 32 + lg * 8), acc4[1]);
      }
      int ncols = ncolss[hd]; const float* B2 = B2s[hd]; float* outp = outs[hd];
#pragma unroll
      for (int c4 = 0; c4 < 2; c4++){
        if (c4 < nct){
          int col = c4 * 16 + l15;
          if (col < ncols){
            float bb = B2[col];
#pragma unroll
            for (int i = 0; i < 4; i++){
              int node = r0 + lg * 4 + i;
              if (node < nh) outp[(size_t)node * ncols + col] = acc4[c4][i] + bb;
            }
          }
        }
      }
    }
  }
}

// ---------------- launch ----------------
extern "C" void kernel_launch(void* const* d_in, const int* in_sizes, int n_in,
                              void* d_out, int out_size, void* d_ws, size_t ws_size,
                              hipStream_t stream){
  (void)n_in;
  const float* x   = (const float*)d_in[0];
  const int*   ei  = (const int*)d_in[1];
  const float* w1l = (const float*)d_in[3];
  const float* w1r = (const float*)d_in[4];
  const float* b1  = (const float*)d_in[5];
  const float* w2l = (const float*)d_in[6];
  const float* w2r = (const float*)d_in[7];
  const float* b2  = (const float*)d_in[8];
  const float* w3l = (const float*)d_in[9];
  const float* w3r = (const float*)d_in[10];
  const float* b3  = (const float*)d_in[11];
  const float* g1w = (const float*)d_in[12];
  const float* g1b = (const float*)d_in[13];
  const float* g1m = (const float*)d_in[14];
  const float* g2w = (const float*)d_in[15];
  const float* g2b = (const float*)d_in[16];
  const float* g2m = (const float*)d_in[17];
  const float* g3w = (const float*)d_in[18];
  const float* g3b = (const float*)d_in[19];
  const float* g3m = (const float*)d_in[20];
  const float* hw1 = (const float*)d_in[21];
  const float* hb1 = (const float*)d_in[22];
  const float* hw2 = (const float*)d_in[23];
  const float* hb2 = (const float*)d_in[24];
  const float* ew1 = (const float*)d_in[25];
  const float* eb1 = (const float*)d_in[26];
  const float* ew2 = (const float*)d_in[27];
  const float* eb2 = (const float*)d_in[28];
  const float* rw1 = (const float*)d_in[29];
  const float* rb1 = (const float*)d_in[30];
  const float* rw2 = (const float*)d_in[31];
  const float* rb2 = (const float*)d_in[32];

  int N  = in_sizes[0];
  int E  = in_sizes[1] / 2;
  int nh = out_size / 35;            // 8 + 18 + 9 outputs per household
  const int* dst = ei + E;           // second row of edge_index
  int tiles = (nh + 63) / 64;
  if (ws_size < (size_t)WS_NEED) return;

  char* wsb = (char*)d_ws;
  double* wsD = (double*)wsb;
  float*  wsB = (float*)(wsb + 8192);
  float*  wsP = (float*)(wsb + 49152);
  unsigned short* wsU = (unsigned short*)(wsb + 81920);
  float* bins2g = wsB + WB_B2;
  float* bins3g = wsB + WB_B3;

  hipMemsetAsync(d_ws, 0, ZERO_BYTES, stream);
  k_prep <<<576, 256, 0, stream>>>(w2r, w3r, hw1, ew1, rw1, hw2, ew2, rw2, wsU);
  k_bins1<<<256, 256, 0, stream>>>(x, dst, wsB, nh);
  k_xmom <<<512, 256, 0, stream>>>(x, wsD, N);
  k_S1   <<<1, 128, 0, stream>>>(x, w1l, w1r, b1, g1w, g1b, g1m, wsB, wsD, wsP, nh, N);
  k_binh1<<<1024, 256, 0, stream>>>(x, dst, wsP, bins2g, nh);
  k_passA<<<512, 256, 0, stream>>>(x, wsP, wsU, b2, wsD, nh, tiles);
  k_S23  <<<1, 256, 0, stream>>>(bins2g, wsB + WB_B1C, wsP + WP_H1S, w2l, w2r, b2,
                                 g2w, g2b, g2m, wsD + WD_SP2, wsD + WD_SQ2,
                                 wsP + WP_C2, wsP + WP_D2F, wsP + WP_H2S, nh, N);
  k_passB<<<512, 256, 0, stream>>>(x, dst, wsP, wsU, b3, wsD, bins3g, nh, tiles);
  k_S23  <<<1, 256, 0, stream>>>(bins3g, wsB + WB_B1C, wsP + WP_H2S, w3l, w3r, b3,
                                 g3w, g3b, g3m, wsD + WD_SP3, wsD + WD_SQ3,
                                 wsP + WP_C3, wsP + WP_D3F, nullptr, nh, N);
  k_passC<<<tiles, 256, 0, stream>>>(x, wsP, wsU, hb1, hb2, eb1, eb2, rb1, rb2,
                                     (float*)d_out, nh, tiles);
}

// Round 4
// 1654.729 us; speedup vs baseline: 3.5064x; 3.5064x over previous
//
// R4: restructure k_passC. R3 profile: passC = whole runtime, MfmaUtil 1%, 12GB HBM
// traffic (7.8GB writes!) at VGPR cap 256 -> scratch spills + weight re-streaming
// (288KB per 16 rows/wave). Fix: runtime hd loop (no 3x unroll), M_rep=2 (32 rows
// per wave per B-load), wave-private LDS arenas, no barriers in passC.
#include <hip/hip_runtime.h>

typedef __bf16 bf16x8 __attribute__((ext_vector_type(8)));
typedef unsigned short u16x8 __attribute__((ext_vector_type(8)));
typedef float f32x4 __attribute__((ext_vector_type(4)));
typedef unsigned short u16a __attribute__((may_alias));
typedef u16x8 u16x8a __attribute__((may_alias));
typedef bf16x8 bf16x8a __attribute__((may_alias));

#define MFMA16(a,b,c) __builtin_amdgcn_mfma_f32_16x16x32_bf16(a,b,c,0,0,0)

// ---------------- ws layout ----------------
// doubles @ byte 0
#define WD_SX   0
#define WD_SXX  1
#define WD_SP2  2
#define WD_SQ2  130
#define WD_SP3  258
#define WD_SQ3  386   // end 514 doubles
// f32 atomics/bins @ byte 8192
#define WB_B1X  0       // 32
#define WB_B1C  32      // 32
#define WB_B2   64      // 27*128
#define WB_B3   (64+27*128)
#define ZERO_BYTES (8192 + (64 + 2*27*128)*4)
// f32 params @ byte 49152
#define WP_A    0
#define WP_B    128
#define WP_C2   256
#define WP_D2F  384
#define WP_C3   512
#define WP_D3F  640
#define WP_H1S  1024
#define WP_H2S  (1024+3456)
// bf16 (ushort) weights @ byte 81920
#define WU_W2RT 0
#define WU_W3RT 16384
#define WU_HW1T 32768
#define WU_EW1T 65536
#define WU_RW1T 98304
#define WU_HW2T 131072   // 16x256 (padded from 8)
#define WU_EW2T 135168   // 32x256 (padded from 18)
#define WU_RW2T 143360   // 16x256 (padded from 9)
#define WU_TOTAL 147456
#define WS_NEED (81920 + WU_TOTAL*2)

__device__ inline unsigned short f2bf(float f){
  union { float f; unsigned u; } v; v.f = f;
  return (unsigned short)((v.u + 0x7FFFu + ((v.u >> 16) & 1u)) >> 16);
}
__device__ inline float bf2f(unsigned short h){
  union { unsigned u; float f; } v; v.u = ((unsigned)h) << 16;
  return v.f;
}
__device__ inline bf16x8 u2b(u16x8 u){ union { u16x8 u; bf16x8 b; } c; c.u = u; return c.b; }

// build the layer-1 A-fragment: row = lane&15 -> node, k = coeff index
__device__ inline bf16x8 h1frag(const float* __restrict__ Ac, const float* __restrict__ Bc,
                                float xv, int kb){
  u16x8 a;
#pragma unroll
  for (int j = 0; j < 8; j++)
    a[j] = f2bf(fmaxf(fmaf(Ac[kb + j], xv, Bc[kb + j]), 0.f));
  return u2b(a);
}
__device__ inline bf16x8 ldg8(const unsigned short* __restrict__ p){
  return *(const bf16x8a*)p;
}
// LDS bf16 tile helpers, XOR row swizzle; may_alias keeps store->load ordered
__device__ inline bf16x8 lda8(const unsigned short* base, int r, int k, int rb){
  int byte = (r * rb + k * 2) ^ ((r & 7) << 4);
  u16x8 u = *(const u16x8a*)((const char*)base + byte);
  return u2b(u);
}
__device__ inline void sth(unsigned short* base, int r, int c, int rb, float v){
  int byte = (r * rb + c * 2) ^ ((r & 7) << 4);
  *(u16a*)((char*)base + byte) = f2bf(v);
}

// ---------------- small kernels ----------------
__global__ void k_prep(const float* __restrict__ w2r, const float* __restrict__ w3r,
                       const float* __restrict__ hw1, const float* __restrict__ ew1,
                       const float* __restrict__ rw1, const float* __restrict__ hw2,
                       const float* __restrict__ ew2, const float* __restrict__ rw2,
                       unsigned short* __restrict__ wsU){
  int i = blockIdx.x * blockDim.x + threadIdx.x;
  if (i < 16384){ int c=i>>7,k=i&127; wsU[WU_W2RT+i]=f2bf(w2r[k*128+c]); return; } i -= 16384;
  if (i < 16384){ int c=i>>7,k=i&127; wsU[WU_W3RT+i]=f2bf(w3r[k*128+c]); return; } i -= 16384;
  if (i < 32768){ int c=i>>7,k=i&127; wsU[WU_HW1T+i]=f2bf(hw1[k*256+c]); return; } i -= 32768;
  if (i < 32768){ int c=i>>7,k=i&127; wsU[WU_EW1T+i]=f2bf(ew1[k*256+c]); return; } i -= 32768;
  if (i < 32768){ int c=i>>7,k=i&127; wsU[WU_RW1T+i]=f2bf(rw1[k*256+c]); return; } i -= 32768;
  if (i < 4096) { int c=i>>8,k=i&255; wsU[WU_HW2T+i]=f2bf(c<8 ? hw2[k*8+c] :0.f); return; } i -= 4096;
  if (i < 8192) { int c=i>>8,k=i&255; wsU[WU_EW2T+i]=f2bf(c<18? ew2[k*18+c]:0.f); return; } i -= 8192;
  if (i < 4096) { int c=i>>8,k=i&255; wsU[WU_RW2T+i]=f2bf(c<9 ? rw2[k*9+c] :0.f); return; }
}

__global__ void k_bins1(const float* __restrict__ x, const int* __restrict__ dst,
                        float* __restrict__ wsB, int nh){
  __shared__ float lb[64];
  if (threadIdx.x < 64) lb[threadIdx.x] = 0.f;
  __syncthreads();
  for (int i = blockIdx.x * blockDim.x + threadIdx.x; i < nh; i += gridDim.x * blockDim.x){
    float xv = x[i];
    int d1 = dst[i] - nh, d2 = dst[i + nh] - nh;
    atomicAdd(&lb[d1], xv);      atomicAdd(&lb[32 + d1], 1.f);
    atomicAdd(&lb[d2], xv);      atomicAdd(&lb[32 + d2], 1.f);
  }
  __syncthreads();
  if (threadIdx.x < 64) atomicAdd(wsB + threadIdx.x, lb[threadIdx.x]); // [0,32)=sum x, [32,64)=cnt
}

__global__ void k_xmom(const float* __restrict__ x, double* __restrict__ wsD, int N){
  double s = 0, q = 0;
  for (int i = blockIdx.x * blockDim.x + threadIdx.x; i < N; i += gridDim.x * blockDim.x){
    double v = x[i]; s += v; q += v * v;
  }
#pragma unroll
  for (int o = 32; o; o >>= 1){ s += __shfl_down(s, o); q += __shfl_down(q, o); }
  if ((threadIdx.x & 63) == 0){ atomicAdd(wsD + WD_SX, s); atomicAdd(wsD + WD_SXX, q); }
}

__global__ void k_S1(const float* __restrict__ x, const float* __restrict__ w1l,
                     const float* __restrict__ w1r, const float* __restrict__ b1,
                     const float* __restrict__ g1w, const float* __restrict__ g1b,
                     const float* __restrict__ g1m, const float* __restrict__ wsB,
                     const double* __restrict__ wsD, float* __restrict__ wsP, int nh, int N){
  __shared__ float pres[27 * 128];
  int c = threadIdx.x;                     // 128 threads
  double Sx = wsD[WD_SX], Sxx = wsD[WD_SXX];
  const float* bx = wsB + WB_B1X; const float* bc = wsB + WB_B1C;
  double sumQ = 0, xs = 0, xs2 = 0, Sm = 0;
  double wl = w1l[c], wr = w1r[c], bb = b1[c];
  for (int j = 0; j < 27; j++){
    double xj = (double)x[nh + j];
    xs += xj; xs2 += xj * xj;
    double mj = (double)bx[j] / fmax((double)bc[j], 1.0);
    Sm += mj;
    double pre = mj * wl + xj * wr + bb;
    pres[j * 128 + c] = (float)pre;
    sumQ += pre * pre;
  }
  double S1 = wr * Sx + (double)N * bb + wl * Sm;
  double mu = S1 / N;
  double Sxh = Sx - xs, Sxxh = Sxx - xs2;
  double Q = wr * wr * Sxxh + 2.0 * wr * bb * Sxh + (double)nh * bb * bb + sumQ;
  double ms = g1m[c];
  double var = Q / N - 2.0 * ms * mu * mu + ms * ms * mu * mu;
  double inv = 1.0 / sqrt(var + 1e-5);
  float C1 = (float)((double)g1w[c] * inv);
  float D1 = (float)((double)g1b[c] - (double)g1w[c] * inv * ms * mu);
  wsP[WP_A + c] = C1 * (float)wr;
  wsP[WP_B + c] = fmaf(C1, (float)bb, D1);
  for (int j = 0; j < 27; j++)
    wsP[WP_H1S + j * 128 + c] = fmaxf(fmaf(C1, pres[j * 128 + c], D1), 0.f);
}

// super-node layer + stats finalize for layers 2/3
__global__ void k_S23(const float* __restrict__ binsNg, const float* __restrict__ cnt,
                      const float* __restrict__ hsup_in, const float* __restrict__ wl,
                      const float* __restrict__ wr, const float* __restrict__ bb,
                      const float* __restrict__ gw, const float* __restrict__ gb,
                      const float* __restrict__ gm, const double* __restrict__ spD,
                      const double* __restrict__ sqD, float* __restrict__ Cout,
                      float* __restrict__ Dfout, float* __restrict__ hsup_out, int nh, int N){
  __shared__ float mloc[27 * 128], hloc[27 * 128], pres[27 * 128];
  __shared__ float sC[128], sD[128];
  int tid = threadIdx.x;                   // 256 threads
  for (int i = tid; i < 27 * 128; i += 256){
    int j = i >> 7;
    mloc[i] = binsNg[i] / fmaxf(cnt[j], 1.f);
    hloc[i] = hsup_in[i];
  }
  __syncthreads();
  int c = tid & 127, g = tid >> 7;
  for (int j = g; j < 27; j += 2){
    float acc = bb[c];
#pragma unroll 4
    for (int k = 0; k < 128; k++)
      acc += mloc[j * 128 + k] * wl[k * 128 + c] + hloc[j * 128 + k] * wr[k * 128 + c];
    pres[j * 128 + c] = acc;
  }
  __syncthreads();
  if (tid < 128){
    double sumP = 0, sumQ = 0;
    for (int j = 0; j < 27; j++){ double p = pres[j * 128 + c]; sumP += p; sumQ += p * p; }
    double mu = (spD[c] + sumP) / N;
    double E2 = (sqD[c] + sumQ) / N;
    double ms = gm[c];
    double var = E2 - 2.0 * ms * mu * mu + ms * ms * mu * mu;
    double inv = 1.0 / sqrt(var + 1e-5);
    float C = (float)((double)gw[c] * inv);
    float D = (float)((double)gb[c] - (double)gw[c] * inv * ms * mu);
    Cout[c] = C;
    Dfout[c] = fmaf(C, bb[c], D);   // folded: h = relu(C*acc + Df), acc excludes bias
    sC[c] = C; sD[c] = D;
  }
  __syncthreads();
  if (hsup_out){
    for (int i = tid; i < 27 * 128; i += 256){
      int cc = i & 127;
      hsup_out[i] = fmaxf(fmaf(sC[cc], pres[i], sD[cc]), 0.f);
    }
  }
}

// bins of h1 by dst (layer-2 super inputs)
__global__ __launch_bounds__(256) void k_binh1(const float* __restrict__ x,
                                               const int* __restrict__ dst,
                                               const float* __restrict__ wsP,
                                               float* __restrict__ bins2g, int nh){
  __shared__ float lb[2][27 * 128];
  int tid = threadIdx.x;
  for (int i = tid; i < 2 * 27 * 128; i += 256) ((float*)lb)[i] = 0.f;
  __syncthreads();
  int c = tid & 127, g = tid >> 7;
  float Ac = wsP[WP_A + c], Bc = wsP[WP_B + c];
  float* mb = lb[g];
  for (int n0 = blockIdx.x * 8 + g * 4; n0 < nh; n0 += gridDim.x * 8){
    float xv[4]; int dd1[4], dd2[4];
#pragma unroll
    for (int u = 0; u < 4; u++){
      int n = n0 + u; bool v = n < nh;
      xv[u] = v ? x[n] : 0.f;
      dd1[u] = v ? dst[n] - nh : 0;
      dd2[u] = v ? dst[n + nh] - nh : 0;
    }
#pragma unroll
    for (int u = 0; u < 4; u++){
      if (n0 + u < nh){
        float h = fmaxf(fmaf(Ac, xv[u], Bc), 0.f);
        mb[dd1[u] * 128 + c] += h;
        mb[dd2[u] * 128 + c] += h;
      }
    }
  }
  __syncthreads();
  for (int i = tid; i < 27 * 128; i += 256) atomicAdd(bins2g + i, lb[0][i] + lb[1][i]);
}

// ---------------- MFMA passes ----------------
__global__ __launch_bounds__(256) void k_passA(const float* __restrict__ x,
    const float* __restrict__ wsP, const unsigned short* __restrict__ wsU,
    const float* __restrict__ b2, double* __restrict__ wsD, int nh, int tiles){
  const float* Ac = wsP + WP_A; const float* Bc = wsP + WP_B;
  const unsigned short* w2rT = wsU + WU_W2RT;
  int l = threadIdx.x & 63, w = threadIdx.x >> 6;
  int l15 = l & 15, lg = l >> 4;
  float s[8], q[8];
#pragma unroll
  for (int i = 0; i < 8; i++){ s[i] = 0; q[i] = 0; }
  for (int t = blockIdx.x; t < tiles; t += gridDim.x){
    int r0 = t * 64 + w * 16;
    int ra = r0 + l15;
    float xv = (ra < nh) ? x[ra] : 0.f;
    bf16x8 af[4];
#pragma unroll
    for (int ks = 0; ks < 4; ks++) af[ks] = h1frag(Ac, Bc, xv, ks * 32 + lg * 8);
#pragma unroll
    for (int ct = 0; ct < 8; ct++){
      f32x4 acc = {0, 0, 0, 0};
#pragma unroll
      for (int ks = 0; ks < 4; ks++)
        acc = MFMA16(af[ks], ldg8(w2rT + (ct * 16 + l15) * 128 + ks * 32 + lg * 8), acc);
      float bb = b2[ct * 16 + l15];
#pragma unroll
      for (int i = 0; i < 4; i++){
        if (r0 + lg * 4 + i < nh){ float p = acc[i] + bb; s[ct] += p; q[ct] += p * p; }
      }
    }
  }
#pragma unroll
  for (int i = 0; i < 8; i++){
    s[i] += __shfl_xor(s[i], 16); s[i] += __shfl_xor(s[i], 32);
    q[i] += __shfl_xor(q[i], 16); q[i] += __shfl_xor(q[i], 32);
  }
  __shared__ float red[2][4][128];
  if (lg == 0){
#pragma unroll
    for (int ct = 0; ct < 8; ct++){ red[0][w][ct * 16 + l15] = s[ct]; red[1][w][ct * 16 + l15] = q[ct]; }
  }
  __syncthreads();
  if (threadIdx.x < 128){
    int c = threadIdx.x;
    atomicAdd(wsD + WD_SP2 + c, (double)(red[0][0][c] + red[0][1][c] + red[0][2][c] + red[0][3][c]));
    atomicAdd(wsD + WD_SQ2 + c, (double)(red[1][0][c] + red[1][1][c] + red[1][2][c] + red[1][3][c]));
  }
}

__global__ __launch_bounds__(256) void k_passB(const float* __restrict__ x,
    const int* __restrict__ dst, const float* __restrict__ wsP,
    const unsigned short* __restrict__ wsU, const float* __restrict__ b3,
    double* __restrict__ wsD, float* __restrict__ bins3g, int nh, int tiles){
  __shared__ float binsW[4][27 * 128];
  __shared__ unsigned short h2all[4][2048];
  __shared__ float red[2][4][128];
  int tid = threadIdx.x;
  for (int i = tid; i < 4 * 27 * 128; i += 256) ((float*)binsW)[i] = 0.f;
  __syncthreads();
  int l = tid & 63, w = tid >> 6, l15 = l & 15, lg = l >> 4;
  unsigned short* h2l = h2all[w];
  const float* Ac = wsP + WP_A; const float* Bc = wsP + WP_B;
  const float* C2 = wsP + WP_C2; const float* D2 = wsP + WP_D2F;
  const unsigned short* w2rT = wsU + WU_W2RT; const unsigned short* w3rT = wsU + WU_W3RT;
  float s[8], q[8];
#pragma unroll
  for (int i = 0; i < 8; i++){ s[i] = 0; q[i] = 0; }
  for (int t = blockIdx.x; t < tiles; t += gridDim.x){
    __syncthreads();   // WAR: protect previous iteration's h2l reads before overwrite
    int r0 = t * 64 + w * 16;
    float xv = (r0 + l15 < nh) ? x[r0 + l15] : 0.f;
    bf16x8 af[4];
#pragma unroll
    for (int ks = 0; ks < 4; ks++) af[ks] = h1frag(Ac, Bc, xv, ks * 32 + lg * 8);
#pragma unroll
    for (int ct = 0; ct < 8; ct++){
      f32x4 acc = {0, 0, 0, 0};
#pragma unroll
      for (int ks = 0; ks < 4; ks++)
        acc = MFMA16(af[ks], ldg8(w2rT + (ct * 16 + l15) * 128 + ks * 32 + lg * 8), acc);
      int c = ct * 16 + l15; float c2 = C2[c], d2 = D2[c];
#pragma unroll
      for (int i = 0; i < 4; i++)
        sth(h2l, lg * 4 + i, c, 256, fmaxf(fmaf(c2, acc[i], d2), 0.f));
    }
    __syncthreads();   // RAW: h2l stores -> a2 loads
    bf16x8 a2[4];
#pragma unroll
    for (int ks = 0; ks < 4; ks++) a2[ks] = lda8(h2l, l15, ks * 32 + lg * 8, 256);
#pragma unroll
    for (int ct = 0; ct < 8; ct++){
      f32x4 acc = {0, 0, 0, 0};
#pragma unroll
      for (int ks = 0; ks < 4; ks++)
        acc = MFMA16(a2[ks], ldg8(w3rT + (ct * 16 + l15) * 128 + ks * 32 + lg * 8), acc);
      float bb = b3[ct * 16 + l15];
#pragma unroll
      for (int i = 0; i < 4; i++){
        if (r0 + lg * 4 + i < nh){ float p = acc[i] + bb; s[ct] += p; q[ct] += p * p; }
      }
    }
    // segment bins of h2 (layer-3 super inputs); wave-private, no race
    for (int rr = 0; rr < 16; rr++){
      int node = r0 + rr;
      if (node < nh){
        int d1 = dst[node] - nh, d2i = dst[node + nh] - nh;
#pragma unroll
        for (int half = 0; half < 2; half++){
          int c = l + half * 64;
          int byte = (rr * 256 + c * 2) ^ ((rr & 7) << 4);
          float hv = bf2f(*(const u16a*)((const char*)h2l + byte));
          binsW[w][d1 * 128 + c] += hv;
          binsW[w][d2i * 128 + c] += hv;
        }
      }
    }
  }
#pragma unroll
  for (int i = 0; i < 8; i++){
    s[i] += __shfl_xor(s[i], 16); s[i] += __shfl_xor(s[i], 32);
    q[i] += __shfl_xor(q[i], 16); q[i] += __shfl_xor(q[i], 32);
  }
  if (lg == 0){
#pragma unroll
    for (int ct = 0; ct < 8; ct++){ red[0][w][ct * 16 + l15] = s[ct]; red[1][w][ct * 16 + l15] = q[ct]; }
  }
  __syncthreads();
  if (tid < 128){
    atomicAdd(wsD + WD_SP3 + tid, (double)(red[0][0][tid] + red[0][1][tid] + red[0][2][tid] + red[0][3][tid]));
    atomicAdd(wsD + WD_SQ3 + tid, (double)(red[1][0][tid] + red[1][1][tid] + red[1][2][tid] + red[1][3][tid]));
  }
  for (int i = tid; i < 27 * 128; i += 256)
    atomicAdd(bins3g + i, binsW[0][i] + binsW[1][i] + binsW[2][i] + binsW[3][i]);
}

// full chain + heads; M_rep=2 (32 rows/wave), runtime head loop, wave-private LDS.
__global__ __launch_bounds__(256) void k_passC(const float* __restrict__ x,
    const float* __restrict__ wsP, const unsigned short* __restrict__ wsU,
    const float* __restrict__ hb1, const float* __restrict__ hb2,
    const float* __restrict__ eb1, const float* __restrict__ eb2,
    const float* __restrict__ rb1, const float* __restrict__ rb2,
    float* __restrict__ out, int nh, int tiles2){
  __shared__ char lds[65536];
  int tid = threadIdx.x;
  int l = tid & 63, w = tid >> 6, l15 = l & 15, lg = l >> 4;
  char* myl = lds + w * 16384;                          // wave-private 16KB arena
  unsigned short* h2l = (unsigned short*)myl;           // 32x128 bf16, rb 256
  unsigned short* h3l = (unsigned short*)(myl + 8192);  // 32x128 bf16, rb 256
  unsigned short* tl  = (unsigned short*)myl;           // 32x256 bf16, rb 512 (overlay)
  const float* Ac = wsP + WP_A;  const float* Bc = wsP + WP_B;
  const float* C2 = wsP + WP_C2; const float* D2 = wsP + WP_D2F;
  const float* C3 = wsP + WP_C3; const float* D3 = wsP + WP_D3F;
  const unsigned short* w2rT = wsU + WU_W2RT; const unsigned short* w3rT = wsU + WU_W3RT;

  for (int t = blockIdx.x; t < tiles2; t += gridDim.x){
    int r0 = t * 128 + w * 32;
    float xv0 = (r0 + l15 < nh)      ? x[r0 + l15]      : 0.f;
    float xv1 = (r0 + 16 + l15 < nh) ? x[r0 + 16 + l15] : 0.f;
    bf16x8 af0[4], af1[4];
#pragma unroll
    for (int ks = 0; ks < 4; ks++){
      af0[ks] = h1frag(Ac, Bc, xv0, ks * 32 + lg * 8);
      af1[ks] = h1frag(Ac, Bc, xv1, ks * 32 + lg * 8);
    }
    // GEMM1 -> h2 (rows 0..31)
#pragma unroll
    for (int ct = 0; ct < 8; ct++){
      bf16x8 b[4];
#pragma unroll
      for (int ks = 0; ks < 4; ks++) b[ks] = ldg8(w2rT + (ct * 16 + l15) * 128 + ks * 32 + lg * 8);
      f32x4 acc0 = {0,0,0,0}, acc1 = {0,0,0,0};
#pragma unroll
      for (int ks = 0; ks < 4; ks++){ acc0 = MFMA16(af0[ks], b[ks], acc0); acc1 = MFMA16(af1[ks], b[ks], acc1); }
      int c = ct * 16 + l15; float c2 = C2[c], d2 = D2[c];
#pragma unroll
      for (int i = 0; i < 4; i++){
        sth(h2l, lg * 4 + i,      c, 256, fmaxf(fmaf(c2, acc0[i], d2), 0.f));
        sth(h2l, 16 + lg * 4 + i, c, 256, fmaxf(fmaf(c2, acc1[i], d2), 0.f));
      }
    }
    // GEMM2 -> h3
    bf16x8 a20[4], a21[4];
#pragma unroll
    for (int ks = 0; ks < 4; ks++){
      a20[ks] = lda8(h2l, l15,      ks * 32 + lg * 8, 256);
      a21[ks] = lda8(h2l, 16 + l15, ks * 32 + lg * 8, 256);
    }
#pragma unroll
    for (int ct = 0; ct < 8; ct++){
      bf16x8 b[4];
#pragma unroll
      for (int ks = 0; ks < 4; ks++) b[ks] = ldg8(w3rT + (ct * 16 + l15) * 128 + ks * 32 + lg * 8);
      f32x4 acc0 = {0,0,0,0}, acc1 = {0,0,0,0};
#pragma unroll
      for (int ks = 0; ks < 4; ks++){ acc0 = MFMA16(a20[ks], b[ks], acc0); acc1 = MFMA16(a21[ks], b[ks], acc1); }
      int c = ct * 16 + l15; float c3 = C3[c], d3 = D3[c];
#pragma unroll
      for (int i = 0; i < 4; i++){
        sth(h3l, lg * 4 + i,      c, 256, fmaxf(fmaf(c3, acc0[i], d3), 0.f));
        sth(h3l, 16 + lg * 4 + i, c, 256, fmaxf(fmaf(c3, acc1[i], d3), 0.f));
      }
    }
    // a3 fragments into registers (before tl overlay clobbers h3l region)
    bf16x8 a30[4], a31[4];
#pragma unroll
    for (int ks = 0; ks < 4; ks++){
      a30[ks] = lda8(h3l, l15,      ks * 32 + lg * 8, 256);
      a31[ks] = lda8(h3l, 16 + l15, ks * 32 + lg * 8, 256);
    }
    // three heads, runtime loop (code size / regs)
#pragma unroll 1
    for (int hd = 0; hd < 3; hd++){
      const unsigned short* W1T = (hd == 0) ? wsU + WU_HW1T : (hd == 1) ? wsU + WU_EW1T : wsU + WU_RW1T;
      const unsigned short* W2T = (hd == 0) ? wsU + WU_HW2T : (hd == 1) ? wsU + WU_EW2T : wsU + WU_RW2T;
      const float* B1 = (hd == 0) ? hb1 : (hd == 1) ? eb1 : rb1;
      const float* B2 = (hd == 0) ? hb2 : (hd == 1) ? eb2 : rb2;
      int ncols = (hd == 0) ? 8 : (hd == 1) ? 18 : 9;
      int nct   = (hd == 1) ? 2 : 1;
      float* outp = (hd == 0) ? out : (hd == 1) ? out + (size_t)nh * 8 : out + (size_t)nh * 26;
      // mid = relu(h3 @ W1 + b1) -> tl (32x256)
#pragma unroll
      for (int ct = 0; ct < 16; ct++){
        bf16x8 b[4];
#pragma unroll
        for (int ks = 0; ks < 4; ks++) b[ks] = ldg8(W1T + (ct * 16 + l15) * 128 + ks * 32 + lg * 8);
        f32x4 acc0 = {0,0,0,0}, acc1 = {0,0,0,0};
#pragma unroll
        for (int ks = 0; ks < 4; ks++){ acc0 = MFMA16(a30[ks], b[ks], acc0); acc1 = MFMA16(a31[ks], b[ks], acc1); }
        int c = ct * 16 + l15; float b1v = B1[c];
#pragma unroll
        for (int i = 0; i < 4; i++){
          sth(tl, lg * 4 + i,      c, 512, fmaxf(acc0[i] + b1v, 0.f));
          sth(tl, 16 + lg * 4 + i, c, 512, fmaxf(acc1[i] + b1v, 0.f));
        }
      }
      // out = mid @ W2 + b2
#pragma unroll
      for (int m = 0; m < 2; m++){
        f32x4 acc4a = {0,0,0,0}, acc4b = {0,0,0,0};
#pragma unroll
        for (int ks = 0; ks < 8; ks++){
          bf16x8 a4 = lda8(tl, m * 16 + l15, ks * 32 + lg * 8, 512);
          acc4a = MFMA16(a4, ldg8(W2T + l15 * 256 + ks * 32 + lg * 8), acc4a);
          if (nct > 1)
            acc4b = MFMA16(a4, ldg8(W2T + (16 + l15) * 256 + ks * 32 + lg * 8), acc4b);
        }
        int col = l15;
        if (col < ncols){
          float bb = B2[col];
#pragma unroll
          for (int i = 0; i < 4; i++){
            int node = r0 + m * 16 + lg * 4 + i;
            if (node < nh) outp[(size_t)node * ncols + col] = acc4a[i] + bb;
          }
        }
        int col2 = 16 + l15;
        if (nct > 1 && col2 < ncols){
          float bb = B2[col2];
#pragma unroll
          for (int i = 0; i < 4; i++){
            int node = r0 + m * 16 + lg * 4 + i;
            if (node < nh) outp[(size_t)node * ncols + col2] = acc4b[i] + bb;
          }
        }
      }
    }
  }
}

// ---------------- launch ----------------
extern "C" void kernel_launch(void* const* d_in, const int* in_sizes, int n_in,
                              void* d_out, int out_size, void* d_ws, size_t ws_size,
                              hipStream_t stream){
  (void)n_in;
  const float* x   = (const float*)d_in[0];
  const int*   ei  = (const int*)d_in[1];
  const float* w1l = (const float*)d_in[3];
  const float* w1r = (const float*)d_in[4];
  const float* b1  = (const float*)d_in[5];
  const float* w2l = (const float*)d_in[6];
  const float* w2r = (const float*)d_in[7];
  const float* b2  = (const float*)d_in[8];
  const float* w3l = (const float*)d_in[9];
  const float* w3r = (const float*)d_in[10];
  const float* b3  = (const float*)d_in[11];
  const float* g1w = (const float*)d_in[12];
  const float* g1b = (const float*)d_in[13];
  const float* g1m = (const float*)d_in[14];
  const float* g2w = (const float*)d_in[15];
  const float* g2b = (const float*)d_in[16];
  const float* g2m = (const float*)d_in[17];
  const float* g3w = (const float*)d_in[18];
  const float* g3b = (const float*)d_in[19];
  const float* g3m = (const float*)d_in[20];
  const float* hw1 = (const float*)d_in[21];
  const float* hb1 = (const float*)d_in[22];
  const float* hw2 = (const float*)d_in[23];
  const float* hb2 = (const float*)d_in[24];
  const float* ew1 = (const float*)d_in[25];
  const float* eb1 = (const float*)d_in[26];
  const float* ew2 = (const float*)d_in[27];
  const float* eb2 = (const float*)d_in[28];
  const float* rw1 = (const float*)d_in[29];
  const float* rb1 = (const float*)d_in[30];
  const float* rw2 = (const float*)d_in[31];
  const float* rb2 = (const float*)d_in[32];

  int N  = in_sizes[0];
  int E  = in_sizes[1] / 2;
  int nh = out_size / 35;            // 8 + 18 + 9 outputs per household
  const int* dst = ei + E;           // second row of edge_index
  int tiles  = (nh + 63) / 64;
  int tiles2 = (nh + 127) / 128;
  if (ws_size < (size_t)WS_NEED) return;

  char* wsb = (char*)d_ws;
  double* wsD = (double*)wsb;
  float*  wsB = (float*)(wsb + 8192);
  float*  wsP = (float*)(wsb + 49152);
  unsigned short* wsU = (unsigned short*)(wsb + 81920);
  float* bins2g = wsB + WB_B2;
  float* bins3g = wsB + WB_B3;

  hipMemsetAsync(d_ws, 0, ZERO_BYTES, stream);
  k_prep <<<576, 256, 0, stream>>>(w2r, w3r, hw1, ew1, rw1, hw2, ew2, rw2, wsU);
  k_bins1<<<256, 256, 0, stream>>>(x, dst, wsB, nh);
  k_xmom <<<512, 256, 0, stream>>>(x, wsD, N);
  k_S1   <<<1, 128, 0, stream>>>(x, w1l, w1r, b1, g1w, g1b, g1m, wsB, wsD, wsP, nh, N);
  k_binh1<<<1024, 256, 0, stream>>>(x, dst, wsP, bins2g, nh);
  k_passA<<<512, 256, 0, stream>>>(x, wsP, wsU, b2, wsD, nh, tiles);
  k_S23  <<<1, 256, 0, stream>>>(bins2g, wsB + WB_B1C, wsP + WP_H1S, w2l, w2r, b2,
                                 g2w, g2b, g2m, wsD + WD_SP2, wsD + WD_SQ2,
                                 wsP + WP_C2, wsP + WP_D2F, wsP + WP_H2S, nh, N);
  k_passB<<<512, 256, 0, stream>>>(x, dst, wsP, wsU, b3, wsD, bins3g, nh, tiles);
  k_S23  <<<1, 256, 0, stream>>>(bins3g, wsB + WB_B1C, wsP + WP_H2S, w3l, w3r, b3,
                                 g3w, g3b, g3m, wsD + WD_SP3, wsD + WD_SQ3,
                                 wsP + WP_C3, wsP + WP_D3F, nullptr, nh, N);
  k_passC<<<tiles2, 256, 0, stream>>>(x, wsP, wsU, hb1, hb2, eb1, eb2, rb1, rb2,
                                      (float*)d_out, nh, tiles2);
}

// Round 5
// 1248.287 us; speedup vs baseline: 4.6480x; 1.3256x over previous
//
// R5: kill passC spills + fold binh1 into passA.
// R4 evidence: VGPR=256 cap, WRITE 1.08GB (out=70MB -> ~1GB scratch), FETCH 523MB
// (spill refills), MfmaUtil 5%. Cause: full unroll of ct loops -> compiler hoists
// 16x16-VGPR B-prefetches. Fix: __launch_bounds__(256,2), #pragma unroll 2 on weight
// loops, share head-W2 B-frags across both M tiles. Also: passA now also bins h1
// (k_binh1 removed) -- one less full pass over the graph.
#include <hip/hip_runtime.h>

typedef __bf16 bf16x8 __attribute__((ext_vector_type(8)));
typedef unsigned short u16x8 __attribute__((ext_vector_type(8)));
typedef float f32x4 __attribute__((ext_vector_type(4)));
typedef unsigned short u16a __attribute__((may_alias));
typedef u16x8 u16x8a __attribute__((may_alias));
typedef bf16x8 bf16x8a __attribute__((may_alias));

#define MFMA16(a,b,c) __builtin_amdgcn_mfma_f32_16x16x32_bf16(a,b,c,0,0,0)

// ---------------- ws layout ----------------
// doubles @ byte 0
#define WD_SX   0
#define WD_SXX  1
#define WD_SP2  2
#define WD_SQ2  130
#define WD_SP3  258
#define WD_SQ3  386   // end 514 doubles
// f32 atomics/bins @ byte 8192
#define WB_B1X  0       // 32
#define WB_B1C  32      // 32
#define WB_B2   64      // 27*128
#define WB_B3   (64+27*128)
#define ZERO_BYTES (8192 + (64 + 2*27*128)*4)
// f32 params @ byte 49152
#define WP_A    0
#define WP_B    128
#define WP_C2   256
#define WP_D2F  384
#define WP_C3   512
#define WP_D3F  640
#define WP_H1S  1024
#define WP_H2S  (1024+3456)
// bf16 (ushort) weights @ byte 81920
#define WU_W2RT 0
#define WU_W3RT 16384
#define WU_HW1T 32768
#define WU_EW1T 65536
#define WU_RW1T 98304
#define WU_HW2T 131072   // 16x256 (padded from 8)
#define WU_EW2T 135168   // 32x256 (padded from 18)
#define WU_RW2T 143360   // 16x256 (padded from 9)
#define WU_TOTAL 147456
#define WS_NEED (81920 + WU_TOTAL*2)

__device__ inline unsigned short f2bf(float f){
  union { float f; unsigned u; } v; v.f = f;
  return (unsigned short)((v.u + 0x7FFFu + ((v.u >> 16) & 1u)) >> 16);
}
__device__ inline float bf2f(unsigned short h){
  union { unsigned u; float f; } v; v.u = ((unsigned)h) << 16;
  return v.f;
}
__device__ inline bf16x8 u2b(u16x8 u){ union { u16x8 u; bf16x8 b; } c; c.u = u; return c.b; }

// build the layer-1 A-fragment: row = lane&15 -> node, k = coeff index
__device__ inline bf16x8 h1frag(const float* __restrict__ Ac, const float* __restrict__ Bc,
                                float xv, int kb){
  u16x8 a;
#pragma unroll
  for (int j = 0; j < 8; j++)
    a[j] = f2bf(fmaxf(fmaf(Ac[kb + j], xv, Bc[kb + j]), 0.f));
  return u2b(a);
}
__device__ inline bf16x8 ldg8(const unsigned short* __restrict__ p){
  return *(const bf16x8a*)p;
}
// LDS bf16 tile helpers, XOR row swizzle; may_alias keeps store->load ordered
__device__ inline bf16x8 lda8(const unsigned short* base, int r, int k, int rb){
  int byte = (r * rb + k * 2) ^ ((r & 7) << 4);
  u16x8 u = *(const u16x8a*)((const char*)base + byte);
  return u2b(u);
}
__device__ inline void sth(unsigned short* base, int r, int c, int rb, float v){
  int byte = (r * rb + c * 2) ^ ((r & 7) << 4);
  *(u16a*)((char*)base + byte) = f2bf(v);
}

// ---------------- small kernels ----------------
__global__ void k_prep(const float* __restrict__ w2r, const float* __restrict__ w3r,
                       const float* __restrict__ hw1, const float* __restrict__ ew1,
                       const float* __restrict__ rw1, const float* __restrict__ hw2,
                       const float* __restrict__ ew2, const float* __restrict__ rw2,
                       unsigned short* __restrict__ wsU){
  int i = blockIdx.x * blockDim.x + threadIdx.x;
  if (i < 16384){ int c=i>>7,k=i&127; wsU[WU_W2RT+i]=f2bf(w2r[k*128+c]); return; } i -= 16384;
  if (i < 16384){ int c=i>>7,k=i&127; wsU[WU_W3RT+i]=f2bf(w3r[k*128+c]); return; } i -= 16384;
  if (i < 32768){ int c=i>>7,k=i&127; wsU[WU_HW1T+i]=f2bf(hw1[k*256+c]); return; } i -= 32768;
  if (i < 32768){ int c=i>>7,k=i&127; wsU[WU_EW1T+i]=f2bf(ew1[k*256+c]); return; } i -= 32768;
  if (i < 32768){ int c=i>>7,k=i&127; wsU[WU_RW1T+i]=f2bf(rw1[k*256+c]); return; } i -= 32768;
  if (i < 4096) { int c=i>>8,k=i&255; wsU[WU_HW2T+i]=f2bf(c<8 ? hw2[k*8+c] :0.f); return; } i -= 4096;
  if (i < 8192) { int c=i>>8,k=i&255; wsU[WU_EW2T+i]=f2bf(c<18? ew2[k*18+c]:0.f); return; } i -= 8192;
  if (i < 4096) { int c=i>>8,k=i&255; wsU[WU_RW2T+i]=f2bf(c<9 ? rw2[k*9+c] :0.f); return; }
}

__global__ void k_bins1(const float* __restrict__ x, const int* __restrict__ dst,
                        float* __restrict__ wsB, int nh){
  __shared__ float lb[64];
  if (threadIdx.x < 64) lb[threadIdx.x] = 0.f;
  __syncthreads();
  for (int i = blockIdx.x * blockDim.x + threadIdx.x; i < nh; i += gridDim.x * blockDim.x){
    float xv = x[i];
    int d1 = dst[i] - nh, d2 = dst[i + nh] - nh;
    atomicAdd(&lb[d1], xv);      atomicAdd(&lb[32 + d1], 1.f);
    atomicAdd(&lb[d2], xv);      atomicAdd(&lb[32 + d2], 1.f);
  }
  __syncthreads();
  if (threadIdx.x < 64) atomicAdd(wsB + threadIdx.x, lb[threadIdx.x]); // [0,32)=sum x, [32,64)=cnt
}

__global__ void k_xmom(const float* __restrict__ x, double* __restrict__ wsD, int N){
  double s = 0, q = 0;
  for (int i = blockIdx.x * blockDim.x + threadIdx.x; i < N; i += gridDim.x * blockDim.x){
    double v = x[i]; s += v; q += v * v;
  }
#pragma unroll
  for (int o = 32; o; o >>= 1){ s += __shfl_down(s, o); q += __shfl_down(q, o); }
  if ((threadIdx.x & 63) == 0){ atomicAdd(wsD + WD_SX, s); atomicAdd(wsD + WD_SXX, q); }
}

__global__ void k_S1(const float* __restrict__ x, const float* __restrict__ w1l,
                     const float* __restrict__ w1r, const float* __restrict__ b1,
                     const float* __restrict__ g1w, const float* __restrict__ g1b,
                     const float* __restrict__ g1m, const float* __restrict__ wsB,
                     const double* __restrict__ wsD, float* __restrict__ wsP, int nh, int N){
  __shared__ float pres[27 * 128];
  int c = threadIdx.x;                     // 128 threads
  double Sx = wsD[WD_SX], Sxx = wsD[WD_SXX];
  const float* bx = wsB + WB_B1X; const float* bc = wsB + WB_B1C;
  double sumQ = 0, xs = 0, xs2 = 0, Sm = 0;
  double wl = w1l[c], wr = w1r[c], bb = b1[c];
  for (int j = 0; j < 27; j++){
    double xj = (double)x[nh + j];
    xs += xj; xs2 += xj * xj;
    double mj = (double)bx[j] / fmax((double)bc[j], 1.0);
    Sm += mj;
    double pre = mj * wl + xj * wr + bb;
    pres[j * 128 + c] = (float)pre;
    sumQ += pre * pre;
  }
  double S1 = wr * Sx + (double)N * bb + wl * Sm;
  double mu = S1 / N;
  double Sxh = Sx - xs, Sxxh = Sxx - xs2;
  double Q = wr * wr * Sxxh + 2.0 * wr * bb * Sxh + (double)nh * bb * bb + sumQ;
  double ms = g1m[c];
  double var = Q / N - 2.0 * ms * mu * mu + ms * ms * mu * mu;
  double inv = 1.0 / sqrt(var + 1e-5);
  float C1 = (float)((double)g1w[c] * inv);
  float D1 = (float)((double)g1b[c] - (double)g1w[c] * inv * ms * mu);
  wsP[WP_A + c] = C1 * (float)wr;
  wsP[WP_B + c] = fmaf(C1, (float)bb, D1);
  for (int j = 0; j < 27; j++)
    wsP[WP_H1S + j * 128 + c] = fmaxf(fmaf(C1, pres[j * 128 + c], D1), 0.f);
}

// super-node layer + stats finalize for layers 2/3
__global__ void k_S23(const float* __restrict__ binsNg, const float* __restrict__ cnt,
                      const float* __restrict__ hsup_in, const float* __restrict__ wl,
                      const float* __restrict__ wr, const float* __restrict__ bb,
                      const float* __restrict__ gw, const float* __restrict__ gb,
                      const float* __restrict__ gm, const double* __restrict__ spD,
                      const double* __restrict__ sqD, float* __restrict__ Cout,
                      float* __restrict__ Dfout, float* __restrict__ hsup_out, int nh, int N){
  __shared__ float mloc[27 * 128], hloc[27 * 128], pres[27 * 128];
  __shared__ float sC[128], sD[128];
  int tid = threadIdx.x;                   // 256 threads
  for (int i = tid; i < 27 * 128; i += 256){
    int j = i >> 7;
    mloc[i] = binsNg[i] / fmaxf(cnt[j], 1.f);
    hloc[i] = hsup_in[i];
  }
  __syncthreads();
  int c = tid & 127, g = tid >> 7;
  for (int j = g; j < 27; j += 2){
    float acc = bb[c];
#pragma unroll 4
    for (int k = 0; k < 128; k++)
      acc += mloc[j * 128 + k] * wl[k * 128 + c] + hloc[j * 128 + k] * wr[k * 128 + c];
    pres[j * 128 + c] = acc;
  }
  __syncthreads();
  if (tid < 128){
    double sumP = 0, sumQ = 0;
    for (int j = 0; j < 27; j++){ double p = pres[j * 128 + c]; sumP += p; sumQ += p * p; }
    double mu = (spD[c] + sumP) / N;
    double E2 = (sqD[c] + sumQ) / N;
    double ms = gm[c];
    double var = E2 - 2.0 * ms * mu * mu + ms * ms * mu * mu;
    double inv = 1.0 / sqrt(var + 1e-5);
    float C = (float)((double)gw[c] * inv);
    float D = (float)((double)gb[c] - (double)gw[c] * inv * ms * mu);
    Cout[c] = C;
    Dfout[c] = fmaf(C, bb[c], D);   // folded: h = relu(C*acc + Df), acc excludes bias
    sC[c] = C; sD[c] = D;
  }
  __syncthreads();
  if (hsup_out){
    for (int i = tid; i < 27 * 128; i += 256){
      int cc = i & 127;
      hsup_out[i] = fmaxf(fmaf(sC[cc], pres[i], sD[cc]), 0.f);
    }
  }
}

// ---------------- MFMA passes ----------------
// passA: pre2 moments via MFMA + h1 bins (binh1 folded in)
__global__ __launch_bounds__(256) void k_passA(const float* __restrict__ x,
    const int* __restrict__ dst, const float* __restrict__ wsP,
    const unsigned short* __restrict__ wsU, const float* __restrict__ b2,
    double* __restrict__ wsD, float* __restrict__ bins2g, int nh, int tiles){
  __shared__ float binsW[4][27 * 128];
  __shared__ float red[2][4][128];
  const float* Ac = wsP + WP_A; const float* Bc = wsP + WP_B;
  const unsigned short* w2rT = wsU + WU_W2RT;
  int tid = threadIdx.x;
  int l = tid & 63, w = tid >> 6;
  int l15 = l & 15, lg = l >> 4;
  for (int i = tid; i < 4 * 27 * 128; i += 256) ((float*)binsW)[i] = 0.f;
  __syncthreads();
  float ac0 = Ac[l], bc0 = Bc[l], ac1 = Ac[l + 64], bc1 = Bc[l + 64];
  float s[8], q[8];
#pragma unroll
  for (int i = 0; i < 8; i++){ s[i] = 0; q[i] = 0; }
  for (int t = blockIdx.x; t < tiles; t += gridDim.x){
    int r0 = t * 64 + w * 16;
    int ra = r0 + l15;
    float xv = (ra < nh) ? x[ra] : 0.f;
    bf16x8 af[4];
#pragma unroll
    for (int ks = 0; ks < 4; ks++) af[ks] = h1frag(Ac, Bc, xv, ks * 32 + lg * 8);
#pragma unroll 2
    for (int ct = 0; ct < 8; ct++){
      f32x4 acc = {0, 0, 0, 0};
#pragma unroll
      for (int ks = 0; ks < 4; ks++)
        acc = MFMA16(af[ks], ldg8(w2rT + (ct * 16 + l15) * 128 + ks * 32 + lg * 8), acc);
      float bb = b2[ct * 16 + l15];
#pragma unroll
      for (int i = 0; i < 4; i++){
        if (r0 + lg * 4 + i < nh){ float p = acc[i] + bb; s[ct] += p; q[ct] += p * p; }
      }
    }
    // h1 bins (wave-private)
    for (int rr = 0; rr < 16; rr++){
      int node = r0 + rr;
      if (node < nh){
        float xr = __shfl(xv, rr);
        int d1 = dst[node] - nh, d2 = dst[node + nh] - nh;
        float h0 = fmaxf(fmaf(ac0, xr, bc0), 0.f);
        float h1v = fmaxf(fmaf(ac1, xr, bc1), 0.f);
        binsW[w][d1 * 128 + l]      += h0;
        binsW[w][d2 * 128 + l]      += h0;
        binsW[w][d1 * 128 + l + 64] += h1v;
        binsW[w][d2 * 128 + l + 64] += h1v;
      }
    }
  }
#pragma unroll
  for (int i = 0; i < 8; i++){
    s[i] += __shfl_xor(s[i], 16); s[i] += __shfl_xor(s[i], 32);
    q[i] += __shfl_xor(q[i], 16); q[i] += __shfl_xor(q[i], 32);
  }
  if (lg == 0){
#pragma unroll
    for (int ct = 0; ct < 8; ct++){ red[0][w][ct * 16 + l15] = s[ct]; red[1][w][ct * 16 + l15] = q[ct]; }
  }
  __syncthreads();
  if (tid < 128){
    atomicAdd(wsD + WD_SP2 + tid, (double)(red[0][0][tid] + red[0][1][tid] + red[0][2][tid] + red[0][3][tid]));
    atomicAdd(wsD + WD_SQ2 + tid, (double)(red[1][0][tid] + red[1][1][tid] + red[1][2][tid] + red[1][3][tid]));
  }
  for (int i = tid; i < 27 * 128; i += 256)
    atomicAdd(bins2g + i, binsW[0][i] + binsW[1][i] + binsW[2][i] + binsW[3][i]);
}

__global__ __launch_bounds__(256) void k_passB(const float* __restrict__ x,
    const int* __restrict__ dst, const float* __restrict__ wsP,
    const unsigned short* __restrict__ wsU, const float* __restrict__ b3,
    double* __restrict__ wsD, float* __restrict__ bins3g, int nh, int tiles){
  __shared__ float binsW[4][27 * 128];
  __shared__ unsigned short h2all[4][2048];
  __shared__ float red[2][4][128];
  int tid = threadIdx.x;
  for (int i = tid; i < 4 * 27 * 128; i += 256) ((float*)binsW)[i] = 0.f;
  __syncthreads();
  int l = tid & 63, w = tid >> 6, l15 = l & 15, lg = l >> 4;
  unsigned short* h2l = h2all[w];
  const float* Ac = wsP + WP_A; const float* Bc = wsP + WP_B;
  const float* C2 = wsP + WP_C2; const float* D2 = wsP + WP_D2F;
  const unsigned short* w2rT = wsU + WU_W2RT; const unsigned short* w3rT = wsU + WU_W3RT;
  float s[8], q[8];
#pragma unroll
  for (int i = 0; i < 8; i++){ s[i] = 0; q[i] = 0; }
  for (int t = blockIdx.x; t < tiles; t += gridDim.x){
    __syncthreads();   // WAR: protect previous iteration's h2l reads before overwrite
    int r0 = t * 64 + w * 16;
    float xv = (r0 + l15 < nh) ? x[r0 + l15] : 0.f;
    bf16x8 af[4];
#pragma unroll
    for (int ks = 0; ks < 4; ks++) af[ks] = h1frag(Ac, Bc, xv, ks * 32 + lg * 8);
#pragma unroll 2
    for (int ct = 0; ct < 8; ct++){
      f32x4 acc = {0, 0, 0, 0};
#pragma unroll
      for (int ks = 0; ks < 4; ks++)
        acc = MFMA16(af[ks], ldg8(w2rT + (ct * 16 + l15) * 128 + ks * 32 + lg * 8), acc);
      int c = ct * 16 + l15; float c2 = C2[c], d2 = D2[c];
#pragma unroll
      for (int i = 0; i < 4; i++)
        sth(h2l, lg * 4 + i, c, 256, fmaxf(fmaf(c2, acc[i], d2), 0.f));
    }
    __syncthreads();   // RAW: h2l stores -> a2 loads
    bf16x8 a2[4];
#pragma unroll
    for (int ks = 0; ks < 4; ks++) a2[ks] = lda8(h2l, l15, ks * 32 + lg * 8, 256);
#pragma unroll 2
    for (int ct = 0; ct < 8; ct++){
      f32x4 acc = {0, 0, 0, 0};
#pragma unroll
      for (int ks = 0; ks < 4; ks++)
        acc = MFMA16(a2[ks], ldg8(w3rT + (ct * 16 + l15) * 128 + ks * 32 + lg * 8), acc);
      float bb = b3[ct * 16 + l15];
#pragma unroll
      for (int i = 0; i < 4; i++){
        if (r0 + lg * 4 + i < nh){ float p = acc[i] + bb; s[ct] += p; q[ct] += p * p; }
      }
    }
    // segment bins of h2 (layer-3 super inputs); wave-private, no race
    for (int rr = 0; rr < 16; rr++){
      int node = r0 + rr;
      if (node < nh){
        int d1 = dst[node] - nh, d2i = dst[node + nh] - nh;
#pragma unroll
        for (int half = 0; half < 2; half++){
          int c = l + half * 64;
          int byte = (rr * 256 + c * 2) ^ ((rr & 7) << 4);
          float hv = bf2f(*(const u16a*)((const char*)h2l + byte));
          binsW[w][d1 * 128 + c] += hv;
          binsW[w][d2i * 128 + c] += hv;
        }
      }
    }
  }
#pragma unroll
  for (int i = 0; i < 8; i++){
    s[i] += __shfl_xor(s[i], 16); s[i] += __shfl_xor(s[i], 32);
    q[i] += __shfl_xor(q[i], 16); q[i] += __shfl_xor(q[i], 32);
  }
  if (lg == 0){
#pragma unroll
    for (int ct = 0; ct < 8; ct++){ red[0][w][ct * 16 + l15] = s[ct]; red[1][w][ct * 16 + l15] = q[ct]; }
  }
  __syncthreads();
  if (tid < 128){
    atomicAdd(wsD + WD_SP3 + tid, (double)(red[0][0][tid] + red[0][1][tid] + red[0][2][tid] + red[0][3][tid]));
    atomicAdd(wsD + WD_SQ3 + tid, (double)(red[1][0][tid] + red[1][1][tid] + red[1][2][tid] + red[1][3][tid]));
  }
  for (int i = tid; i < 27 * 128; i += 256)
    atomicAdd(bins3g + i, binsW[0][i] + binsW[1][i] + binsW[2][i] + binsW[3][i]);
}

// full chain + heads; M_rep=2 (32 rows/wave), runtime head loop, wave-private LDS.
__global__ __launch_bounds__(256, 2) void k_passC(const float* __restrict__ x,
    const float* __restrict__ wsP, const unsigned short* __restrict__ wsU,
    const float* __restrict__ hb1, const float* __restrict__ hb2,
    const float* __restrict__ eb1, const float* __restrict__ eb2,
    const float* __restrict__ rb1, const float* __restrict__ rb2,
    float* __restrict__ out, int nh, int tiles2){
  __shared__ char lds[65536];
  int tid = threadIdx.x;
  int l = tid & 63, w = tid >> 6, l15 = l & 15, lg = l >> 4;
  char* myl = lds + w * 16384;                          // wave-private 16KB arena
  unsigned short* h2l = (unsigned short*)myl;           // 32x128 bf16, rb 256
  unsigned short* h3l = (unsigned short*)(myl + 8192);  // 32x128 bf16, rb 256
  unsigned short* tl  = (unsigned short*)myl;           // 32x256 bf16, rb 512 (overlay)
  const float* Ac = wsP + WP_A;  const float* Bc = wsP + WP_B;
  const float* C2 = wsP + WP_C2; const float* D2 = wsP + WP_D2F;
  const float* C3 = wsP + WP_C3; const float* D3 = wsP + WP_D3F;
  const unsigned short* w2rT = wsU + WU_W2RT; const unsigned short* w3rT = wsU + WU_W3RT;

  for (int t = blockIdx.x; t < tiles2; t += gridDim.x){
    int r0 = t * 128 + w * 32;
    float xv0 = (r0 + l15 < nh)      ? x[r0 + l15]      : 0.f;
    float xv1 = (r0 + 16 + l15 < nh) ? x[r0 + 16 + l15] : 0.f;
    bf16x8 af0[4], af1[4];
#pragma unroll
    for (int ks = 0; ks < 4; ks++){
      af0[ks] = h1frag(Ac, Bc, xv0, ks * 32 + lg * 8);
      af1[ks] = h1frag(Ac, Bc, xv1, ks * 32 + lg * 8);
    }
    // GEMM1 -> h2 (rows 0..31)
#pragma unroll 2
    for (int ct = 0; ct < 8; ct++){
      bf16x8 b[4];
#pragma unroll
      for (int ks = 0; ks < 4; ks++) b[ks] = ldg8(w2rT + (ct * 16 + l15) * 128 + ks * 32 + lg * 8);
      f32x4 acc0 = {0,0,0,0}, acc1 = {0,0,0,0};
#pragma unroll
      for (int ks = 0; ks < 4; ks++){ acc0 = MFMA16(af0[ks], b[ks], acc0); acc1 = MFMA16(af1[ks], b[ks], acc1); }
      int c = ct * 16 + l15; float c2 = C2[c], d2 = D2[c];
#pragma unroll
      for (int i = 0; i < 4; i++){
        sth(h2l, lg * 4 + i,      c, 256, fmaxf(fmaf(c2, acc0[i], d2), 0.f));
        sth(h2l, 16 + lg * 4 + i, c, 256, fmaxf(fmaf(c2, acc1[i], d2), 0.f));
      }
    }
    // GEMM2 -> h3
    bf16x8 a20[4], a21[4];
#pragma unroll
    for (int ks = 0; ks < 4; ks++){
      a20[ks] = lda8(h2l, l15,      ks * 32 + lg * 8, 256);
      a21[ks] = lda8(h2l, 16 + l15, ks * 32 + lg * 8, 256);
    }
#pragma unroll 2
    for (int ct = 0; ct < 8; ct++){
      bf16x8 b[4];
#pragma unroll
      for (int ks = 0; ks < 4; ks++) b[ks] = ldg8(w3rT + (ct * 16 + l15) * 128 + ks * 32 + lg * 8);
      f32x4 acc0 = {0,0,0,0}, acc1 = {0,0,0,0};
#pragma unroll
      for (int ks = 0; ks < 4; ks++){ acc0 = MFMA16(a20[ks], b[ks], acc0); acc1 = MFMA16(a21[ks], b[ks], acc1); }
      int c = ct * 16 + l15; float c3 = C3[c], d3 = D3[c];
#pragma unroll
      for (int i = 0; i < 4; i++){
        sth(h3l, lg * 4 + i,      c, 256, fmaxf(fmaf(c3, acc0[i], d3), 0.f));
        sth(h3l, 16 + lg * 4 + i, c, 256, fmaxf(fmaf(c3, acc1[i], d3), 0.f));
      }
    }
    // a3 fragments into registers (before tl overlay clobbers h2l/h3l region)
    bf16x8 a30[4], a31[4];
#pragma unroll
    for (int ks = 0; ks < 4; ks++){
      a30[ks] = lda8(h3l, l15,      ks * 32 + lg * 8, 256);
      a31[ks] = lda8(h3l, 16 + l15, ks * 32 + lg * 8, 256);
    }
    // three heads, runtime loop (code size / regs)
#pragma unroll 1
    for (int hd = 0; hd < 3; hd++){
      const unsigned short* W1T = (hd == 0) ? wsU + WU_HW1T : (hd == 1) ? wsU + WU_EW1T : wsU + WU_RW1T;
      const unsigned short* W2T = (hd == 0) ? wsU + WU_HW2T : (hd == 1) ? wsU + WU_EW2T : wsU + WU_RW2T;
      const float* B1 = (hd == 0) ? hb1 : (hd == 1) ? eb1 : rb1;
      const float* B2 = (hd == 0) ? hb2 : (hd == 1) ? eb2 : rb2;
      int ncols = (hd == 0) ? 8 : (hd == 1) ? 18 : 9;
      bool two = (hd == 1);
      float* outp = (hd == 0) ? out : (hd == 1) ? out + (size_t)nh * 8 : out + (size_t)nh * 26;
      // mid = relu(h3 @ W1 + b1) -> tl (32x256)
#pragma unroll 2
      for (int ct = 0; ct < 16; ct++){
        bf16x8 b[4];
#pragma unroll
        for (int ks = 0; ks < 4; ks++) b[ks] = ldg8(W1T + (ct * 16 + l15) * 128 + ks * 32 + lg * 8);
        f32x4 acc0 = {0,0,0,0}, acc1 = {0,0,0,0};
#pragma unroll
        for (int ks = 0; ks < 4; ks++){ acc0 = MFMA16(a30[ks], b[ks], acc0); acc1 = MFMA16(a31[ks], b[ks], acc1); }
        int c = ct * 16 + l15; float b1v = B1[c];
#pragma unroll
        for (int i = 0; i < 4; i++){
          sth(tl, lg * 4 + i,      c, 512, fmaxf(acc0[i] + b1v, 0.f));
          sth(tl, 16 + lg * 4 + i, c, 512, fmaxf(acc1[i] + b1v, 0.f));
        }
      }
      // out = mid @ W2 + b2 ; share B-frags across the two M tiles
      f32x4 accA0 = {0,0,0,0}, accA1 = {0,0,0,0};
      f32x4 accB0 = {0,0,0,0}, accB1 = {0,0,0,0};
#pragma unroll 4
      for (int ks = 0; ks < 8; ks++){
        bf16x8 b0 = ldg8(W2T + l15 * 256 + ks * 32 + lg * 8);
        bf16x8 a40 = lda8(tl, l15,      ks * 32 + lg * 8, 512);
        bf16x8 a41 = lda8(tl, 16 + l15, ks * 32 + lg * 8, 512);
        accA0 = MFMA16(a40, b0, accA0);
        accA1 = MFMA16(a41, b0, accA1);
        if (two){
          bf16x8 b1f = ldg8(W2T + (16 + l15) * 256 + ks * 32 + lg * 8);
          accB0 = MFMA16(a40, b1f, accB0);
          accB1 = MFMA16(a41, b1f, accB1);
        }
      }
      int col = l15;
      if (col < ncols){
        float bb = B2[col];
#pragma unroll
        for (int i = 0; i < 4; i++){
          int n0 = r0 + lg * 4 + i, n1 = r0 + 16 + lg * 4 + i;
          if (n0 < nh) outp[(size_t)n0 * ncols + col] = accA0[i] + bb;
          if (n1 < nh) outp[(size_t)n1 * ncols + col] = accA1[i] + bb;
        }
      }
      int col2 = 16 + l15;
      if (two && col2 < ncols){
        float bb = B2[col2];
#pragma unroll
        for (int i = 0; i < 4; i++){
          int n0 = r0 + lg * 4 + i, n1 = r0 + 16 + lg * 4 + i;
          if (n0 < nh) outp[(size_t)n0 * ncols + col2] = accB0[i] + bb;
          if (n1 < nh) outp[(size_t)n1 * ncols + col2] = accB1[i] + bb;
        }
      }
    }
  }
}

// ---------------- launch ----------------
extern "C" void kernel_launch(void* const* d_in, const int* in_sizes, int n_in,
                              void* d_out, int out_size, void* d_ws, size_t ws_size,
                              hipStream_t stream){
  (void)n_in;
  const float* x   = (const float*)d_in[0];
  const int*   ei  = (const int*)d_in[1];
  const float* w1l = (const float*)d_in[3];
  const float* w1r = (const float*)d_in[4];
  const float* b1  = (const float*)d_in[5];
  const float* w2l = (const float*)d_in[6];
  const float* w2r = (const float*)d_in[7];
  const float* b2  = (const float*)d_in[8];
  const float* w3l = (const float*)d_in[9];
  const float* w3r = (const float*)d_in[10];
  const float* b3  = (const float*)d_in[11];
  const float* g1w = (const float*)d_in[12];
  const float* g1b = (const float*)d_in[13];
  const float* g1m = (const float*)d_in[14];
  const float* g2w = (const float*)d_in[15];
  const float* g2b = (const float*)d_in[16];
  const float* g2m = (const float*)d_in[17];
  const float* g3w = (const float*)d_in[18];
  const float* g3b = (const float*)d_in[19];
  const float* g3m = (const float*)d_in[20];
  const float* hw1 = (const float*)d_in[21];
  const float* hb1 = (const float*)d_in[22];
  const float* hw2 = (const float*)d_in[23];
  const float* hb2 = (const float*)d_in[24];
  const float* ew1 = (const float*)d_in[25];
  const float* eb1 = (const float*)d_in[26];
  const float* ew2 = (const float*)d_in[27];
  const float* eb2 = (const float*)d_in[28];
  const float* rw1 = (const float*)d_in[29];
  const float* rb1 = (const float*)d_in[30];
  const float* rw2 = (const float*)d_in[31];
  const float* rb2 = (const float*)d_in[32];

  int N  = in_sizes[0];
  int E  = in_sizes[1] / 2;
  int nh = out_size / 35;            // 8 + 18 + 9 outputs per household
  const int* dst = ei + E;           // second row of edge_index
  int tiles  = (nh + 63) / 64;
  int tiles2 = (nh + 127) / 128;
  if (ws_size < (size_t)WS_NEED) return;

  char* wsb = (char*)d_ws;
  double* wsD = (double*)wsb;
  float*  wsB = (float*)(wsb + 8192);
  float*  wsP = (float*)(wsb + 49152);
  unsigned short* wsU = (unsigned short*)(wsb + 81920);
  float* bins2g = wsB + WB_B2;
  float* bins3g = wsB + WB_B3;

  hipMemsetAsync(d_ws, 0, ZERO_BYTES, stream);
  k_prep <<<576, 256, 0, stream>>>(w2r, w3r, hw1, ew1, rw1, hw2, ew2, rw2, wsU);
  k_bins1<<<256, 256, 0, stream>>>(x, dst, wsB, nh);
  k_xmom <<<512, 256, 0, stream>>>(x, wsD, N);
  k_S1   <<<1, 128, 0, stream>>>(x, w1l, w1r, b1, g1w, g1b, g1m, wsB, wsD, wsP, nh, N);
  k_passA<<<512, 256, 0, stream>>>(x, dst, wsP, wsU, b2, wsD, bins2g, nh, tiles);
  k_S23  <<<1, 256, 0, stream>>>(bins2g, wsB + WB_B1C, wsP + WP_H1S, w2l, w2r, b2,
                                 g2w, g2b, g2m, wsD + WD_SP2, wsD + WD_SQ2,
                                 wsP + WP_C2, wsP + WP_D2F, wsP + WP_H2S, nh, N);
  k_passB<<<512, 256, 0, stream>>>(x, dst, wsP, wsU, b3, wsD, bins3g, nh, tiles);
  k_S23  <<<1, 256, 0, stream>>>(bins3g, wsB + WB_B1C, wsP + WP_H2S, w3l, w3r, b3,
                                 g3w, g3b, g3m, wsD + WD_SP3, wsD + WD_SQ3,
                                 wsP + WP_C3, wsP + WP_D3F, nullptr, nh, N);
  k_passC<<<tiles2, 256, 0, stream>>>(x, wsP, wsU, hb1, hb2, eb1, eb2, rb1, rb2,
                                      (float*)d_out, nh, tiles2);
}